// Round 6
// baseline (271.178 us; speedup 1.0000x reference)
//
#include <hip/hip_runtime.h>

typedef unsigned int u32;
typedef unsigned long long u64;
typedef unsigned char u8;

#define NB 4
#define T_ANCH 261120
#define NCAND 2048          // candidates per image (4 levels x 512)
#define KSEL 512
#define POSTN 512
#define LOG_MAXF 4.135166556742356f
#define NMS_TH 0.7f
#define LVL_OFF_F 8192.0f
#define BINS 4096           // top-12 bits of mono32
#define EQCAP 8192          // tie-bin capacity (expected ~50-700 occupants)
#define K5_BLOCKS 2048      // 4 img x 4 lvl x 128 sub-blocks
#define K1_BLOCKS 256       // 64 chunk-blocks per image (48/12/3/1 per level)

__device__ __forceinline__ u32 mono32(float f){
  u32 u = __float_as_uint(f);
  return (u & 0x80000000u) ? ~u : (u | 0x80000000u);
}
__device__ __forceinline__ int lvl_hw(int lvl){ return 65536 >> (2*lvl); }
__device__ __forceinline__ int lvl_off(int lvl){
  return (lvl>0?196608:0) + (lvl>1?49152:0) + (lvl>2?12288:0);
}
// chunk-block mapping: bx in [0,256): b = bx>>6, c = bx&63
__device__ __forceinline__ void k1_map(int bx, int& b, int& lvl, int& ch){
  b = bx >> 6;
  int c = bx & 63;
  if (c < 48){ lvl = 0; ch = c; }
  else if (c < 60){ lvl = 1; ch = c - 48; }
  else if (c < 63){ lvl = 2; ch = c - 60; }
  else { lvl = 3; ch = 0; }
}

// ---------------------------------------------------------------------------
// K1: per-chunk LDS histogram -> atomicAdd into 16 per-(b,lvl) global hists;
// the LAST block of each group (done-counter) does the threshold walk inline.
// ---------------------------------------------------------------------------
__global__ __launch_bounds__(1024) void k1_hist_thresh(
    const float* __restrict__ o0, const float* __restrict__ o1,
    const float* __restrict__ o2, const float* __restrict__ o3,
    u32* __restrict__ hist16, u32* __restrict__ done16,
    u32* __restrict__ gb0, u32* __restrict__ gcA)
{
  int b, lvl, ch;
  k1_map(blockIdx.x, b, lvl, ch);
  int bid16 = b*4 + lvl;
  int nch = (lvl==0?48 : lvl==1?12 : lvl==2?3 : 1);
  const float* ob = (lvl==0)?o0 : (lvl==1)?o1 : (lvl==2)?o2 : o3;
  int hw = lvl_hw(lvl);
  int size = 3*hw;
  int n4 = size >> 2;
  int i4 = ch*1024 + threadIdx.x;
  __shared__ u32 hist[BINS];
  __shared__ u32 coarse[64];
  __shared__ int s_last;
  for (int i = threadIdx.x; i < BINS; i += 1024) hist[i] = 0;
  __syncthreads();
  if (i4 < n4){
    float4 v = ((const float4*)(ob + (size_t)b*size))[i4];
    atomicAdd(&hist[mono32(v.x) >> 20], 1u);
    atomicAdd(&hist[mono32(v.y) >> 20], 1u);
    atomicAdd(&hist[mono32(v.z) >> 20], 1u);
    atomicAdd(&hist[mono32(v.w) >> 20], 1u);
  }
  __syncthreads();
  u32* gh = hist16 + (size_t)bid16*BINS;
  for (int i = threadIdx.x; i < BINS; i += 1024){
    u32 c = hist[i];
    if (c) atomicAdd(&gh[i], c);
  }
  __syncthreads();                      // all lanes' atomics drained (vmcnt)
  if (threadIdx.x == 0){
    __threadfence();
    u32 d = atomicAdd(&done16[bid16], 1u);
    s_last = (d == (u32)(nch - 1)) ? 1 : 0;
  }
  __syncthreads();
  if (!s_last) return;

  // ---- last block of the group: merged hist -> threshold walk ----
  __threadfence();
  for (int i = threadIdx.x; i < BINS; i += 1024)
    hist[i] = __hip_atomic_load(&gh[i], __ATOMIC_RELAXED, __HIP_MEMORY_SCOPE_AGENT);
  __syncthreads();
  int t = threadIdx.x;
  if (t < 64){
    u32 s = 0;
    for (int z = 0; z < 64; ++z) s += hist[t*64 + z];
    coarse[t] = s;
  }
  __syncthreads();
  if (t == 0){
    u32 acc = 0;
    int cb = 63;
    while (acc + coarse[cb] < (u32)KSEL){ acc += coarse[cb]; --cb; }
    int z = cb*64 + 63;
    while (acc + hist[z] < (u32)KSEL){ acc += hist[z]; --z; }
    gb0[bid16] = (u32)z;
    gcA[bid16] = acc;
  }
}

// ---------------------------------------------------------------------------
// K2: classify chunk elements vs b0. LDS lists + ONE global reservation per
// list per block. Emits PERMUTED index j = pix*3 + a.
// ---------------------------------------------------------------------------
__global__ __launch_bounds__(1024) void k2_classify(
    const float* __restrict__ o0, const float* __restrict__ o1,
    const float* __restrict__ o2, const float* __restrict__ o3,
    const u32* __restrict__ gb0,
    u32* __restrict__ emitcnt, u32* __restrict__ tiecnt,
    int* __restrict__ cand_j, u64* __restrict__ gtie)
{
  int b, lvl, ch;
  k1_map(blockIdx.x, b, lvl, ch);
  int bid16 = b*4 + lvl;
  const float* ob = (lvl==0)?o0 : (lvl==1)?o1 : (lvl==2)?o2 : o3;
  int hw = lvl_hw(lvl);
  int size = 3*hw;
  int n4 = size >> 2;
  int i4 = ch*1024 + threadIdx.x;

  __shared__ u32 dbuf[KSEL];
  __shared__ u64 tbuf[4096];
  __shared__ u32 dn, tn, dbase, tbase;
  if (threadIdx.x == 0){ dn = 0; tn = 0; }
  __syncthreads();

  u32 b0v = gb0[bid16];
  if (i4 < n4){
    float4 v = ((const float4*)(ob + (size_t)b*size))[i4];
    int L = i4 << 2;
    int a = L / hw;                 // hw % 4 == 0 -> same a for all 4
    int pix = L - a*hw;
    int j0 = pix*3 + a;
    float vv[4] = {v.x, v.y, v.z, v.w};
    #pragma unroll
    for (int q = 0; q < 4; ++q){
      u32 m = mono32(vv[q]);
      u32 bin = m >> 20;
      int j = j0 + 3*q;
      if (bin > b0v){
        u32 s = atomicAdd(&dn, 1u);
        if (s < (u32)KSEL) dbuf[s] = (u32)j;
      } else if (bin == b0v){
        u32 s = atomicAdd(&tn, 1u);
        if (s < 4096u) tbuf[s] = ((u64)m << 32) | (u32)(~(u32)j);
      }
    }
  }
  __syncthreads();
  if (threadIdx.x == 0){
    dbase = dn ? atomicAdd(&emitcnt[bid16], dn) : 0u;
    tbase = tn ? atomicAdd(&tiecnt[bid16], tn) : 0u;
  }
  __syncthreads();
  for (u32 x = threadIdx.x; x < dn; x += 1024){
    u32 s = dbase + x;
    if (s < (u32)KSEL) cand_j[bid16*KSEL + s] = (int)dbuf[x];
  }
  for (u32 x = threadIdx.x; x < tn; x += 1024){
    u32 s = tbase + x;
    if (s < (u32)EQCAP) gtie[(size_t)bid16*EQCAP + s] = tbuf[x];
  }
}

// ---------------------------------------------------------------------------
// K3: per-(b,lvl) tie rank-select + decode of the pair's 512 candidates.
// 16 blocks x 512 threads.
// ---------------------------------------------------------------------------
__global__ __launch_bounds__(512) void k3_tie_decode(
    const u64* __restrict__ gtie, const u32* __restrict__ tiecnt,
    const u32* __restrict__ gcA, const int* __restrict__ cand_j,
    const float* __restrict__ o0, const float* __restrict__ o1,
    const float* __restrict__ o2, const float* __restrict__ o3,
    const float* __restrict__ d0, const float* __restrict__ d1,
    const float* __restrict__ d2, const float* __restrict__ d3,
    const float* __restrict__ anchors,
    float* __restrict__ cscore, u32* __restrict__ csmono,
    u64* __restrict__ ctb, float* __restrict__ cbox, u8* __restrict__ cvalid)
{
  int bid = blockIdx.x;               // 16 = (b,lvl)
  int t = threadIdx.x;
  __shared__ u64 eq[EQCAP];           // 64 KB
  __shared__ u32 wbuf[KSEL];
  __shared__ int jlist[KSEL];
  __shared__ u32 wn;
  u32 n = tiecnt[bid]; if (n > (u32)EQCAP) n = (u32)EQCAP;
  u32 cA = gcA[bid];
  u32 k = (u32)KSEL - cA;
  if (t == 0) wn = 0;
  for (int i = t; i < KSEL; i += 512) jlist[i] = 0;
  for (u32 i = t; i < n; i += 512) eq[i] = gtie[(size_t)bid*EQCAP + i];
  __syncthreads();
  for (u32 i = t; i < n; i += 512){
    u64 ki = eq[i];
    u32 r = 0;
    for (u32 m = 0; m < n; ++m) r += (eq[m] > ki) ? 1u : 0u;
    if (r < k){
      u32 s = atomicAdd(&wn, 1u);
      if (s < (u32)KSEL) wbuf[s] = (u32)(~(u32)ki);
    }
  }
  __syncthreads();
  u32 w = wn;
  for (u32 i = t; i < cA; i += 512)
    if (i < (u32)KSEL) jlist[i] = cand_j[bid*KSEL + i];
  for (u32 x = t; x < w; x += 512){
    u32 s = cA + x;
    if (s < (u32)KSEL) jlist[s] = (int)wbuf[x];
  }
  __syncthreads();

  // ---- decode this pair's 512 candidates ----
  {
    int c = bid*KSEL + t;             // t in [0,512)
    int b = bid >> 2, lvl = bid & 3;
    int j = jlist[t];
    int hw = lvl_hw(lvl);
    u32 pix = (u32)j / 3u;
    u32 a = (u32)j - pix*3u;
    const float* ob = (lvl==0)?o0 : (lvl==1)?o1 : (lvl==2)?o2 : o3;
    const float* dl = (lvl==0)?d0 : (lvl==1)?d1 : (lvl==2)?d2 : d3;

    float ov = ob[(size_t)(b*3 + (int)a)*hw + pix];
    size_t dbase = ((size_t)(b*3 + (int)a)*6)*(size_t)hw + pix;
    float dx  = dl[dbase + 0*(size_t)hw];
    float dy  = dl[dbase + 1*(size_t)hw];
    float dw  = dl[dbase + 2*(size_t)hw];
    float dh  = dl[dbase + 3*(size_t)hw];
    float dsn = dl[dbase + 4*(size_t)hw];
    float dcs = dl[dbase + 5*(size_t)hw];
    int tt = lvl_off(lvl) + j;
    const float* an = anchors + ((size_t)b*T_ANCH + tt)*5;
    float ax=an[0], ay=an[1], aw=an[2], ah=an[3], aa=an[4];
    dw = fminf(dw, LOG_MAXF); dh = fminf(dh, LOG_MAXF);
    float cx = ax + dx*aw;
    float cy = ay + dy*ah;
    float ww = aw * expf(dw);
    float hh = ah * expf(dh);
    float ang = aa + atan2f(dsn, dcs);
    double sd = 1.0 / (1.0 + exp(-(double)ov));
    float sc = (float)sd;
    bool valid = (ww >= 1e-3f) && (hh >= 1e-3f) && (sc >= 0.0f);
    cscore[c] = sc;
    csmono[c] = valid ? mono32(sc) : 0u;      // invalid => -inf (stable by tb)
    // tiebreak: level asc, obj desc, idx asc (== reference positional order)
    ctb[c] = ((u64)lvl << 50) | ((u64)(u32)(~mono32(ov)) << 18) | (u64)(u32)j;
    cvalid[c] = valid ? 1 : 0;
    float* bb = cbox + (size_t)c*5;
    bb[0]=cx; bb[1]=cy; bb[2]=ww; bb[3]=hh; bb[4]=ang;
  }
}

// ---------------------------------------------------------------------------
// K4: per-image exact RANK-SORT scatter over 256 blocks. Also zeroes the
// mask/rowflag region and scatters each rank into its per-(img,lvl) list
// (order irrelevant: K5 emits (min,max) rank pairs).
// ---------------------------------------------------------------------------
__global__ __launch_bounds__(256) void k4_rank(
    const u32* __restrict__ csmono, const u64* __restrict__ ctb,
    const float* __restrict__ cscore, const float* __restrict__ cbox,
    const u8* __restrict__ cvalid,
    float* __restrict__ sscore, float* __restrict__ sbox,
    float* __restrict__ geom, float4* __restrict__ aabb4,
    u8* __restrict__ svalid, u64* __restrict__ maskz, u64* __restrict__ rowflagz,
    u32* __restrict__ lvlcnt, u32* __restrict__ lvlidx)
{
  int b   = blockIdx.x >> 6;          // image
  int blk = blockIdx.x & 63;          // 64 blocks per image, 32 elems each
  __shared__ u32 sm[NCAND];
  __shared__ u64 stb[NCAND];
  __shared__ u32 cnt[32][8];
  // zero 8 KB slice of mask (total NB*NCAND*32 u64 = 262144 = 256 blocks*1024)
  {
    u64* mz = maskz + (size_t)blockIdx.x * 1024;
    for (int x = threadIdx.x; x < 1024; x += 256) mz[x] = 0ull;
    if (threadIdx.x == 0 && blockIdx.x < NB*32) rowflagz[blockIdx.x] = 0ull;
  }
  for (int k = threadIdx.x; k < NCAND; k += 256){
    sm[k]  = csmono[b*NCAND + k];
    stb[k] = ctb[b*NCAND + k];
  }
  __syncthreads();
  int esub = threadIdx.x >> 3;        // 0..31 element within block
  int ssub = threadIdx.x & 7;         // 0..7 scan slice
  int id = blk*32 + esub;
  u32 ms = sm[id];
  u64 mt = stb[id];
  u32 r = 0;
  #pragma unroll 8
  for (int it = 0; it < 256; ++it){
    int m = it*8 + ssub;
    u32 s2 = sm[m]; u64 t2 = stb[m];
    r += ((s2 > ms) || (s2 == ms && t2 < mt)) ? 1u : 0u;
  }
  cnt[esub][ssub] = r;
  __syncthreads();
  if (ssub == 0){
    u32 rank = 0;
    #pragma unroll
    for (int q = 0; q < 8; ++q) rank += cnt[esub][q];
    int gsrc = b*NCAND + id;
    int gdst = b*NCAND + (int)rank;
    sscore[gdst] = cscore[gsrc];
    svalid[gdst] = cvalid[gsrc];
    float b0 = cbox[(size_t)gsrc*5+0], b1 = cbox[(size_t)gsrc*5+1];
    float b2 = cbox[(size_t)gsrc*5+2], b3 = cbox[(size_t)gsrc*5+3];
    float b4 = cbox[(size_t)gsrc*5+4];
    float* sb = sbox + (size_t)gdst*5;
    sb[0]=b0; sb[1]=b1; sb[2]=b2; sb[3]=b3; sb[4]=b4;
    int lvl = (int)((mt >> 50) & 3ull);
    // per-(img,lvl) rank list (unordered)
    u32 pos = atomicAdd(&lvlcnt[b*4 + lvl], 1u);
    if (pos < (u32)KSEL) lvlidx[(u32)(b*4 + lvl)*KSEL + pos] = (u32)rank;
    float offv = (float)lvl * LVL_OFF_F;
    float cx = b0 + offv, cy = b1 + offv, w=b2, h=b3, ang=b4;
    float cc = cosf(ang), sn = sinf(ang);
    float hx = 0.5f*w, hy = 0.5f*h;
    float x0 = cx + hx*cc - hy*sn, y0 = cy + hx*sn + hy*cc;
    float x1 = cx - hx*cc - hy*sn, y1 = cy - hx*sn + hy*cc;
    float x2 = cx - hx*cc + hy*sn, y2 = cy - hx*sn - hy*cc;
    float x3 = cx + hx*cc + hy*sn, y3 = cy + hx*sn - hy*cc;
    float minx = fminf(fminf(x0,x1),fminf(x2,x3));
    float maxx = fmaxf(fmaxf(x0,x1),fmaxf(x2,x3));
    float miny = fminf(fminf(y0,y1),fminf(y2,y3));
    float maxy = fmaxf(fmaxf(y0,y1),fmaxf(y2,y3));
    float* g = geom + (size_t)gdst*16;
    g[0]=minx; g[1]=maxx; g[2]=miny; g[3]=maxy; g[4]=w*h;
    g[5]=x0; g[6]=y0; g[7]=x1; g[8]=y1; g[9]=x2; g[10]=y2; g[11]=x3; g[12]=y3;
    aabb4[gdst] = make_float4(minx, maxx, miny, maxy);
  }
}

// ---------------------------------------------------------------------------
// K5: level-grouped pair scan. Each block owns 4 mirrored rows of one
// (img,lvl) 512-entry list; AABBs+areas staged in LDS (inner loop has no
// memory latency). Survivor filter is the exact-safe IoU upper bound
// iou>TH  =>  (1+TH)*interAABB > TH*(Ai+Aj); only survivors get the full
// clip. Cross-level pairs are impossible (LVL_OFF construction).
// ---------------------------------------------------------------------------
__device__ __forceinline__ void emit_pt(float* ox, float* oy, int oc, float x, float y){
  #pragma unroll
  for (int s = 0; s < 8; ++s) if (s == oc){ ox[s] = x; oy[s] = y; }
}

__device__ float quad_inter(const float* ca, const float* cb){
  float px[8], py[8];
  #pragma unroll
  for (int q = 0; q < 8; ++q){ px[q]=0.f; py[q]=0.f; }
  #pragma unroll
  for (int q = 0; q < 4; ++q){ px[q]=ca[2*q]; py[q]=ca[2*q+1]; }
  int cnt = 4;
  #pragma unroll
  for (int e = 0; e < 4; ++e){
    float p1x = cb[2*e],         p1y = cb[2*e+1];
    float p2x = cb[(2*e+2)&7],   p2y = cb[(2*e+3)&7];
    float ex = p2x-p1x, ey = p2y-p1y;
    float d[8];
    #pragma unroll
    for (int q = 0; q < 8; ++q) d[q] = ex*(py[q]-p1y) - ey*(px[q]-p1x);
    float ox[8], oy[8];
    #pragma unroll
    for (int q = 0; q < 8; ++q){ ox[q]=0.f; oy[q]=0.f; }
    int oc = 0;
    #pragma unroll
    for (int q = 0; q < 8; ++q){
      if (q < cnt){
        bool last = (q+1 >= cnt);
        float dn  = last ? d[0]  : d[(q+1)&7];
        bool in0 = (d[q] >= 0.0f), in1 = (dn >= 0.0f);
        if (in0){ emit_pt(ox,oy,oc,px[q],py[q]); oc++; }
        if (in0 != in1){
          float pnx = last ? px[0] : px[(q+1)&7];
          float pny = last ? py[0] : py[(q+1)&7];
          float den = d[q] - dn;
          float t = d[q] / ((den == 0.0f) ? 1.0f : den);
          emit_pt(ox,oy,oc, px[q] + t*(pnx-px[q]), py[q] + t*(pny-py[q]));
          oc++;
        }
      }
    }
    cnt = (oc > 8) ? 8 : oc;
    #pragma unroll
    for (int q = 0; q < 8; ++q){ px[q]=ox[q]; py[q]=oy[q]; }
  }
  if (cnt < 3) return 0.0f;
  float s = 0.0f;
  #pragma unroll
  for (int q = 0; q < 8; ++q){
    if (q < cnt){
      bool last = (q+1 >= cnt);
      float pnx = last ? px[0] : px[(q+1)&7];
      float pny = last ? py[0] : py[(q+1)&7];
      s += px[q]*pny - pnx*py[q];
    }
  }
  return 0.5f*fabsf(s);
}

__global__ __launch_bounds__(256) void k5_pairs(
    const u32* __restrict__ lvlidx,
    const float4* __restrict__ aabb4, const float* __restrict__ geom,
    u64* __restrict__ mask, u64* __restrict__ rowflag)
{
  __shared__ u32   s_idx[KSEL];          // 2 KB ranks of this (img,lvl)
  __shared__ float4 s_ab[KSEL];          // 8 KB AABBs
  __shared__ float  s_ar[KSEL];          // 2 KB areas
  __shared__ u32   lbuf[1024];           // 4 KB; max pairs/block = 1022
  __shared__ u32 lcnt;
  const int t = threadIdx.x;
  if (t == 0) lcnt = 0;
  int img = blockIdx.x >> 9;             // 512 blocks per image
  int r9  = blockIdx.x & 511;
  int lvl = r9 >> 7;                     // 128 blocks per level
  int kk  = r9 & 127;
  int lane = t & 63;
  const int base = (img*4 + lvl)*KSEL;
  for (int q = t; q < KSEL; q += 256){
    u32 rk = lvlidx[base + q];
    s_idx[q] = rk;
    s_ab[q]  = aabb4[img*NCAND + rk];
    s_ar[q]  = geom[((size_t)(img*NCAND + rk))*16 + 4];
  }
  __syncthreads();
  int rows[4] = {2*kk, 2*kk + 1, 510 - 2*kk, 511 - 2*kk};
  #pragma unroll
  for (int r = 0; r < 4; ++r){
    int p = rows[r];
    float4 gi = s_ab[p];
    float  ai = s_ar[p];
    for (int q = p + 1 + t; q < KSEL; q += 256){
      float4 gj = s_ab[q];
      float w = fminf(gi.y, gj.y) - fmaxf(gi.x, gj.x);
      float h = fminf(gi.w, gj.w) - fmaxf(gi.z, gj.z);
      bool pass = (w > 0.0f) && (h > 0.0f);
      if (pass){
        float iA = w*h;
        float S  = ai + s_ar[q];
        // exact-safe: iou>TH implies (1+TH)*iA > TH*S; keep with slack
        pass = ((1.0f + NMS_TH)*iA >= NMS_TH*S*(1.0f - 1e-5f));
      }
      u64 bm = __ballot(pass);
      if (bm){
        int leader = __ffsll((long long)bm) - 1;
        u32 bs = 0;
        if (lane == leader) bs = atomicAdd(&lcnt, (u32)__popcll(bm));
        bs = (u32)__shfl((int)bs, leader);
        if (pass){
          u32 off = (u32)__popcll(bm & ((1ull << lane) - 1ull));
          lbuf[bs + off] = (u32)((p << 9) | q);
        }
      }
    }
  }
  __syncthreads();
  u32 n = lcnt;
  for (u32 x = t; x < n; x += 256){
    u32 pr = lbuf[x];
    int p = (int)(pr >> 9), q = (int)(pr & 511);
    u32 ri = s_idx[p], rj = s_idx[q];
    u32 i = ri < rj ? ri : rj;
    u32 j = ri < rj ? rj : ri;
    const float* gi = geom + ((size_t)(img*NCAND + (int)i))*16;
    const float* gj = geom + ((size_t)(img*NCAND + (int)j))*16;
    float inter = quad_inter(gi+5, gj+5);
    float iou = inter / (gi[4] + gj[4] - inter + 1e-7f);
    if (iou > NMS_TH){
      atomicOr(&mask[((size_t)(img*NCAND + (int)i))*32 + (j >> 6)], 1ull << (j & 63));
      atomicOr(&rowflag[(size_t)img*32 + (i >> 6)], 1ull << (i & 63));
    }
  }
}

// ---------------------------------------------------------------------------
// K6: sparse greedy suppression + output (R2-proven version, 8-deep).
// ---------------------------------------------------------------------------
__global__ __launch_bounds__(1024) void k6_nms_out(
    const u64* __restrict__ mask, const u64* __restrict__ rowflag,
    const u8* __restrict__ svalid,
    const float* __restrict__ sbox, const float* __restrict__ sscore,
    float* __restrict__ out)
{
  int b = blockIdx.x;
  __shared__ u32 fid[NCAND];
  __shared__ u32 wcnt[32], wpref[32];
  __shared__ u64 s_kept[32];
  __shared__ u32 pref[32];
  __shared__ u32 s_F;
  int t = threadIdx.x;
  int wid = t >> 6, lane = t & 63;

  // ---- compact flagged row ids (ascending: word-major, bit-major) ----
  if (t < 32) wcnt[t] = (u32)__popcll(rowflag[b*32 + t]);
  __syncthreads();
  if (t == 0){
    u32 run = 0;
    for (int w = 0; w < 32; ++w){ wpref[w] = run; run += wcnt[w]; }
    s_F = run;
  }
  __syncthreads();
  if (t < 32){
    u64 fw = rowflag[b*32 + t];
    u32 o = wpref[t];
    while (fw){
      int bpos = __builtin_ctzll(fw);
      fid[o++] = (u32)(t*64 + bpos);
      fw &= fw - 1;
    }
  }
  // zero-fill output concurrently (independent of the walk)
  for (int x = t; x < POSTN*5; x += 1024) out[(size_t)b*POSTN*5 + x] = 0.0f;
  for (int x = t; x < POSTN;   x += 1024) out[(size_t)NB*POSTN*5 + b*POSTN + x] = 0.0f;
  __syncthreads();

  if (wid == 0){
    // sup init from svalid: lane l<32 builds word l (lanes 32-63 mirror)
    u32 slo = 0, shi = 0;
    {
      int wl = lane & 31;
      u64 w = 0;
      for (int q = 0; q < 64; ++q)
        if (!svalid[b*NCAND + wl*64 + q]) w |= (1ull << q);
      slo = (u32)w; shi = (u32)(w >> 32);
    }
    u32 F = s_F;
    const u64* mb = mask + ((size_t)b*NCAND)*32;
    for (u32 f = 0; f < F; f += 8){
      u32 myfid = 0;
      if (f + (lane & 7) < F) myfid = fid[f + (lane & 7)];
      // prefetch the 8 rows (lane&31 owns one u64 word per row)
      u64 v[8];
      #pragma unroll
      for (int q = 0; q < 8; ++q){
        if (f + q < F){
          u32 fq = (u32)__builtin_amdgcn_readlane((int)myfid, q);
          v[q] = mb[(size_t)fq*32 + (lane & 31)];
        } else v[q] = 0ull;
      }
      #pragma unroll
      for (int q = 0; q < 8; ++q){
        if (f + q < F){
          u32 i = (u32)__builtin_amdgcn_readlane((int)myfid, q);
          int wi = (int)(i >> 6);                  // wave-uniform
          u32 wlo = (u32)__builtin_amdgcn_readlane((int)slo, wi);
          u32 whi = (u32)__builtin_amdgcn_readlane((int)shi, wi);
          u64 w = ((u64)whi << 32) | wlo;
          u32 keep = (u32)((~w >> (i & 63)) & 1ull);
          u64 vm = v[q] & (0ull - (u64)keep);      // branchless
          slo |= (u32)vm; shi |= (u32)(vm >> 32);
        }
      }
    }
    if (lane < 32) s_kept[lane] = ~(((u64)shi << 32) | slo);
  }
  __syncthreads();

  if (t < 32) pref[t] = (u32)__popcll(s_kept[t]);
  __syncthreads();
  if (t == 0){
    u32 run = 0;
    for (int w = 0; w < 32; ++w){ u32 tv = pref[w]; pref[w] = run; run += tv; }
  }
  __syncthreads();
  for (int i = t; i < NCAND; i += 1024){
    u64 kw = s_kept[i >> 6];
    if ((kw >> (i & 63)) & 1ull){
      u32 rank = pref[i >> 6] + (u32)__popcll(kw & ((1ull << (i & 63)) - 1ull));
      if (rank < POSTN){
        const float* bp = sbox + ((size_t)(b*NCAND + i))*5;
        float* op = out + ((size_t)(b*POSTN + rank))*5;
        op[0]=bp[0]; op[1]=bp[1]; op[2]=bp[2]; op[3]=bp[3]; op[4]=bp[4];
        out[(size_t)NB*POSTN*5 + b*POSTN + rank] = sscore[b*NCAND + i];
      }
    }
  }
}

// ---------------------------------------------------------------------------
extern "C" void kernel_launch(void* const* d_in, const int* in_sizes, int n_in,
                              void* d_out, int out_size, void* d_ws, size_t ws_size,
                              hipStream_t stream)
{
  (void)out_size; (void)ws_size;
  const float *obj[4] = {nullptr,nullptr,nullptr,nullptr};
  const float *dlt[4] = {nullptr,nullptr,nullptr,nullptr};
  const float *anchors = nullptr;
  for (int i = 0; i < n_in; ++i){
    int s = in_sizes[i];
    const float* p = (const float*)d_in[i];
    switch (s){
      case 786432:  obj[0] = p; break;
      case 4718592: dlt[0] = p; break;
      case 196608:  obj[1] = p; break;
      case 1179648: dlt[1] = p; break;
      case 49152:   obj[2] = p; break;
      case 294912:  dlt[2] = p; break;
      case 12288:   obj[3] = p; break;
      case 73728:   dlt[3] = p; break;
      case 5222400: anchors = p; break;
      default: break;
    }
  }

  char* wsb = (char*)d_ws;
  size_t off = 0;
  auto alloc = [&](size_t bytes)->void*{
    size_t cur = (off + 255) & ~(size_t)255;
    off = cur + bytes;
    return (void*)(wsb + cur);
  };
  int*   cand_j = (int*)  alloc(16*KSEL*sizeof(int));
  float* cscore = (float*)alloc((size_t)NB*NCAND*sizeof(float));
  u32*   csmono = (u32*)  alloc((size_t)NB*NCAND*sizeof(u32));
  u64*   ctb    = (u64*)  alloc((size_t)NB*NCAND*sizeof(u64));
  float* cbox   = (float*)alloc((size_t)NB*NCAND*5*sizeof(float));
  u8*    cvalid = (u8*)   alloc((size_t)NB*NCAND);
  float* sscore = (float*)alloc((size_t)NB*NCAND*sizeof(float));
  float* sbox   = (float*)alloc((size_t)NB*NCAND*5*sizeof(float));
  u8*    svalid = (u8*)   alloc((size_t)NB*NCAND);
  float* geom   = (float*)alloc((size_t)NB*NCAND*16*sizeof(float));
  float4* aabb4 = (float4*)alloc((size_t)NB*NCAND*sizeof(float4));
  u64*   gtie   = (u64*)  alloc((size_t)16*EQCAP*sizeof(u64));
  u64*   maskp  = (u64*)  alloc((size_t)NB*NCAND*32*sizeof(u64));   // zeroed by k4
  u64*   rowflag= (u64*)  alloc((size_t)NB*32*sizeof(u64));         // zeroed by k4
  u32*   lvlidx = (u32*)  alloc((size_t)16*KSEL*sizeof(u32));       // written by k4
  u32*   gb0    = (u32*)  alloc(16*sizeof(u32));
  u32*   gcA    = (u32*)  alloc(16*sizeof(u32));
  // ---- contiguous zero region (memset): hist16 | done16 | emitc | tiec | lvlcnt
  u32*   hist16 = (u32*)  alloc((size_t)16*BINS*sizeof(u32));
  u32*   done16 = (u32*)  alloc(16*sizeof(u32));
  u32*   emitc  = (u32*)  alloc(16*sizeof(u32));
  u32*   tiec   = (u32*)  alloc(16*sizeof(u32));
  u32*   lvlcnt = (u32*)  alloc(16*sizeof(u32));
  size_t zero_len = (size_t)((wsb + off) - (char*)hist16);

  hipMemsetAsync(hist16, 0, zero_len, stream);

  hipLaunchKernelGGL(k1_hist_thresh, dim3(K1_BLOCKS), dim3(1024), 0, stream,
                     obj[0], obj[1], obj[2], obj[3], hist16, done16, gb0, gcA);
  hipLaunchKernelGGL(k2_classify, dim3(K1_BLOCKS), dim3(1024), 0, stream,
                     obj[0], obj[1], obj[2], obj[3], gb0, emitc, tiec,
                     cand_j, gtie);
  hipLaunchKernelGGL(k3_tie_decode, dim3(16), dim3(512), 0, stream,
                     gtie, tiec, gcA, cand_j,
                     obj[0], obj[1], obj[2], obj[3],
                     dlt[0], dlt[1], dlt[2], dlt[3],
                     anchors, cscore, csmono, ctb, cbox, cvalid);
  hipLaunchKernelGGL(k4_rank, dim3(256), dim3(256), 0, stream,
                     csmono, ctb, cscore, cbox, cvalid, sscore, sbox, geom,
                     aabb4, svalid, maskp, rowflag, lvlcnt, lvlidx);
  hipLaunchKernelGGL(k5_pairs, dim3(K5_BLOCKS), dim3(256), 0, stream,
                     lvlidx, aabb4, geom, maskp, rowflag);
  hipLaunchKernelGGL(k6_nms_out, dim3(4), dim3(1024), 0, stream,
                     maskp, rowflag, svalid, sbox, sscore, (float*)d_out);
}

// Round 7
// 184.362 us; speedup vs baseline: 1.4709x; 1.4709x over previous
//
#include <hip/hip_runtime.h>

typedef unsigned int u32;
typedef unsigned long long u64;
typedef unsigned char u8;

#define NB 4
#define T_ANCH 261120
#define NCAND 2048          // candidates per image (4 levels x 512)
#define KSEL 512
#define POSTN 512
#define LOG_MAXF 4.135166556742356f
#define NMS_TH 0.7f
#define LVL_OFF_F 8192.0f
#define BINS 4096           // top-12 bits of mono32
#define EQCAP 8192          // tie-bin capacity (expected ~50-700 occupants)
#define K5_BLOCKS 2048      // 4 img x 4 lvl x 128 sub-blocks
#define K1_BLOCKS 256       // 64 chunk-blocks per image (48/12/3/1 per level)

__device__ __forceinline__ u32 mono32(float f){
  u32 u = __float_as_uint(f);
  return (u & 0x80000000u) ? ~u : (u | 0x80000000u);
}
__device__ __forceinline__ int lvl_hw(int lvl){ return 65536 >> (2*lvl); }
__device__ __forceinline__ int lvl_off(int lvl){
  return (lvl>0?196608:0) + (lvl>1?49152:0) + (lvl>2?12288:0);
}
// chunk-block mapping: bx in [0,256): b = bx>>6, c = bx&63
__device__ __forceinline__ void k1_map(int bx, int& b, int& lvl, int& ch){
  b = bx >> 6;
  int c = bx & 63;
  if (c < 48){ lvl = 0; ch = c; }
  else if (c < 60){ lvl = 1; ch = c - 48; }
  else if (c < 63){ lvl = 2; ch = c - 60; }
  else { lvl = 3; ch = 0; }
}

// ---------------------------------------------------------------------------
// K1: per-chunk LDS histogram -> atomicAdd into 16 per-(b,lvl) global hists;
// the LAST block of each group (done-counter) does the threshold walk inline.
// ---------------------------------------------------------------------------
__global__ __launch_bounds__(1024) void k1_hist_thresh(
    const float* __restrict__ o0, const float* __restrict__ o1,
    const float* __restrict__ o2, const float* __restrict__ o3,
    u32* __restrict__ hist16, u32* __restrict__ done16,
    u32* __restrict__ gb0, u32* __restrict__ gcA)
{
  int b, lvl, ch;
  k1_map(blockIdx.x, b, lvl, ch);
  int bid16 = b*4 + lvl;
  int nch = (lvl==0?48 : lvl==1?12 : lvl==2?3 : 1);
  const float* ob = (lvl==0)?o0 : (lvl==1)?o1 : (lvl==2)?o2 : o3;
  int hw = lvl_hw(lvl);
  int size = 3*hw;
  int n4 = size >> 2;
  int i4 = ch*1024 + threadIdx.x;
  __shared__ u32 hist[BINS];
  __shared__ u32 coarse[64];
  __shared__ int s_last;
  for (int i = threadIdx.x; i < BINS; i += 1024) hist[i] = 0;
  __syncthreads();
  if (i4 < n4){
    float4 v = ((const float4*)(ob + (size_t)b*size))[i4];
    atomicAdd(&hist[mono32(v.x) >> 20], 1u);
    atomicAdd(&hist[mono32(v.y) >> 20], 1u);
    atomicAdd(&hist[mono32(v.z) >> 20], 1u);
    atomicAdd(&hist[mono32(v.w) >> 20], 1u);
  }
  __syncthreads();
  u32* gh = hist16 + (size_t)bid16*BINS;
  for (int i = threadIdx.x; i < BINS; i += 1024){
    u32 c = hist[i];
    if (c) atomicAdd(&gh[i], c);
  }
  __syncthreads();                      // all lanes' atomics drained (vmcnt)
  if (threadIdx.x == 0){
    __threadfence();
    u32 d = atomicAdd(&done16[bid16], 1u);
    s_last = (d == (u32)(nch - 1)) ? 1 : 0;
  }
  __syncthreads();
  if (!s_last) return;

  // ---- last block of the group: merged hist -> threshold walk ----
  __threadfence();
  for (int i = threadIdx.x; i < BINS; i += 1024)
    hist[i] = __hip_atomic_load(&gh[i], __ATOMIC_RELAXED, __HIP_MEMORY_SCOPE_AGENT);
  __syncthreads();
  int t = threadIdx.x;
  if (t < 64){
    u32 s = 0;
    for (int z = 0; z < 64; ++z) s += hist[t*64 + z];
    coarse[t] = s;
  }
  __syncthreads();
  if (t == 0){
    u32 acc = 0;
    int cb = 63;
    while (acc + coarse[cb] < (u32)KSEL){ acc += coarse[cb]; --cb; }
    int z = cb*64 + 63;
    while (acc + hist[z] < (u32)KSEL){ acc += hist[z]; --z; }
    gb0[bid16] = (u32)z;
    gcA[bid16] = acc;
  }
}

// ---------------------------------------------------------------------------
// K2: classify chunk elements vs b0. LDS lists + ONE global reservation per
// list per block. Emits PERMUTED index j = pix*3 + a.
// ---------------------------------------------------------------------------
__global__ __launch_bounds__(1024) void k2_classify(
    const float* __restrict__ o0, const float* __restrict__ o1,
    const float* __restrict__ o2, const float* __restrict__ o3,
    const u32* __restrict__ gb0,
    u32* __restrict__ emitcnt, u32* __restrict__ tiecnt,
    int* __restrict__ cand_j, u64* __restrict__ gtie)
{
  int b, lvl, ch;
  k1_map(blockIdx.x, b, lvl, ch);
  int bid16 = b*4 + lvl;
  const float* ob = (lvl==0)?o0 : (lvl==1)?o1 : (lvl==2)?o2 : o3;
  int hw = lvl_hw(lvl);
  int size = 3*hw;
  int n4 = size >> 2;
  int i4 = ch*1024 + threadIdx.x;

  __shared__ u32 dbuf[KSEL];
  __shared__ u64 tbuf[4096];
  __shared__ u32 dn, tn, dbase, tbase;
  if (threadIdx.x == 0){ dn = 0; tn = 0; }
  __syncthreads();

  u32 b0v = gb0[bid16];
  if (i4 < n4){
    float4 v = ((const float4*)(ob + (size_t)b*size))[i4];
    int L = i4 << 2;
    int a = L / hw;                 // hw % 4 == 0 -> same a for all 4
    int pix = L - a*hw;
    int j0 = pix*3 + a;
    float vv[4] = {v.x, v.y, v.z, v.w};
    #pragma unroll
    for (int q = 0; q < 4; ++q){
      u32 m = mono32(vv[q]);
      u32 bin = m >> 20;
      int j = j0 + 3*q;
      if (bin > b0v){
        u32 s = atomicAdd(&dn, 1u);
        if (s < (u32)KSEL) dbuf[s] = (u32)j;
      } else if (bin == b0v){
        u32 s = atomicAdd(&tn, 1u);
        if (s < 4096u) tbuf[s] = ((u64)m << 32) | (u32)(~(u32)j);
      }
    }
  }
  __syncthreads();
  if (threadIdx.x == 0){
    dbase = dn ? atomicAdd(&emitcnt[bid16], dn) : 0u;
    tbase = tn ? atomicAdd(&tiecnt[bid16], tn) : 0u;
  }
  __syncthreads();
  for (u32 x = threadIdx.x; x < dn; x += 1024){
    u32 s = dbase + x;
    if (s < (u32)KSEL) cand_j[bid16*KSEL + s] = (int)dbuf[x];
  }
  for (u32 x = threadIdx.x; x < tn; x += 1024){
    u32 s = tbase + x;
    if (s < (u32)EQCAP) gtie[(size_t)bid16*EQCAP + s] = tbuf[x];
  }
}

// ---------------------------------------------------------------------------
// K3: per-(b,lvl) tie rank-select + decode of the pair's 512 candidates.
// 16 blocks x 512 threads.
// ---------------------------------------------------------------------------
__global__ __launch_bounds__(512) void k3_tie_decode(
    const u64* __restrict__ gtie, const u32* __restrict__ tiecnt,
    const u32* __restrict__ gcA, const int* __restrict__ cand_j,
    const float* __restrict__ o0, const float* __restrict__ o1,
    const float* __restrict__ o2, const float* __restrict__ o3,
    const float* __restrict__ d0, const float* __restrict__ d1,
    const float* __restrict__ d2, const float* __restrict__ d3,
    const float* __restrict__ anchors,
    float* __restrict__ cscore, u32* __restrict__ csmono,
    u64* __restrict__ ctb, float* __restrict__ cbox, u8* __restrict__ cvalid)
{
  int bid = blockIdx.x;               // 16 = (b,lvl)
  int t = threadIdx.x;
  __shared__ u64 eq[EQCAP];           // 64 KB
  __shared__ u32 wbuf[KSEL];
  __shared__ int jlist[KSEL];
  __shared__ u32 wn;
  u32 n = tiecnt[bid]; if (n > (u32)EQCAP) n = (u32)EQCAP;
  u32 cA = gcA[bid];
  u32 k = (u32)KSEL - cA;
  if (t == 0) wn = 0;
  for (int i = t; i < KSEL; i += 512) jlist[i] = 0;
  for (u32 i = t; i < n; i += 512) eq[i] = gtie[(size_t)bid*EQCAP + i];
  __syncthreads();
  for (u32 i = t; i < n; i += 512){
    u64 ki = eq[i];
    u32 r = 0;
    for (u32 m = 0; m < n; ++m) r += (eq[m] > ki) ? 1u : 0u;
    if (r < k){
      u32 s = atomicAdd(&wn, 1u);
      if (s < (u32)KSEL) wbuf[s] = (u32)(~(u32)ki);
    }
  }
  __syncthreads();
  u32 w = wn;
  for (u32 i = t; i < cA; i += 512)
    if (i < (u32)KSEL) jlist[i] = cand_j[bid*KSEL + i];
  for (u32 x = t; x < w; x += 512){
    u32 s = cA + x;
    if (s < (u32)KSEL) jlist[s] = (int)wbuf[x];
  }
  __syncthreads();

  // ---- decode this pair's 512 candidates ----
  {
    int c = bid*KSEL + t;             // t in [0,512)
    int b = bid >> 2, lvl = bid & 3;
    int j = jlist[t];
    int hw = lvl_hw(lvl);
    u32 pix = (u32)j / 3u;
    u32 a = (u32)j - pix*3u;
    const float* ob = (lvl==0)?o0 : (lvl==1)?o1 : (lvl==2)?o2 : o3;
    const float* dl = (lvl==0)?d0 : (lvl==1)?d1 : (lvl==2)?d2 : d3;

    float ov = ob[(size_t)(b*3 + (int)a)*hw + pix];
    size_t dbase = ((size_t)(b*3 + (int)a)*6)*(size_t)hw + pix;
    float dx  = dl[dbase + 0*(size_t)hw];
    float dy  = dl[dbase + 1*(size_t)hw];
    float dw  = dl[dbase + 2*(size_t)hw];
    float dh  = dl[dbase + 3*(size_t)hw];
    float dsn = dl[dbase + 4*(size_t)hw];
    float dcs = dl[dbase + 5*(size_t)hw];
    int tt = lvl_off(lvl) + j;
    const float* an = anchors + ((size_t)b*T_ANCH + tt)*5;
    float ax=an[0], ay=an[1], aw=an[2], ah=an[3], aa=an[4];
    dw = fminf(dw, LOG_MAXF); dh = fminf(dh, LOG_MAXF);
    float cx = ax + dx*aw;
    float cy = ay + dy*ah;
    float ww = aw * expf(dw);
    float hh = ah * expf(dh);
    float ang = aa + atan2f(dsn, dcs);
    double sd = 1.0 / (1.0 + exp(-(double)ov));
    float sc = (float)sd;
    bool valid = (ww >= 1e-3f) && (hh >= 1e-3f) && (sc >= 0.0f);
    cscore[c] = sc;
    csmono[c] = valid ? mono32(sc) : 0u;      // invalid => -inf (stable by tb)
    // tiebreak: level asc, obj desc, idx asc (== reference positional order)
    ctb[c] = ((u64)lvl << 50) | ((u64)(u32)(~mono32(ov)) << 18) | (u64)(u32)j;
    cvalid[c] = valid ? 1 : 0;
    float* bb = cbox + (size_t)c*5;
    bb[0]=cx; bb[1]=cy; bb[2]=ww; bb[3]=hh; bb[4]=ang;
  }
}

// ---------------------------------------------------------------------------
// K4: per-image exact RANK-SORT scatter over 256 blocks. Also zeroes the
// mask/rowflag region, and writes the per-(img,lvl) rank list via PLAIN
// STOREs: source slot id = lvl*512 + slot (bijective), so
// lvlidx[(b*4 + id>>9)*KSEL + (id&511)] = rank needs no atomic.
// (R6 lesson: 512-deep same-address atomic chains cost ~110 us.)
// ---------------------------------------------------------------------------
__global__ __launch_bounds__(256) void k4_rank(
    const u32* __restrict__ csmono, const u64* __restrict__ ctb,
    const float* __restrict__ cscore, const float* __restrict__ cbox,
    const u8* __restrict__ cvalid,
    float* __restrict__ sscore, float* __restrict__ sbox,
    float* __restrict__ geom, float4* __restrict__ aabb4,
    u8* __restrict__ svalid, u64* __restrict__ maskz, u64* __restrict__ rowflagz,
    u32* __restrict__ lvlidx)
{
  int b   = blockIdx.x >> 6;          // image
  int blk = blockIdx.x & 63;          // 64 blocks per image, 32 elems each
  __shared__ u32 sm[NCAND];
  __shared__ u64 stb[NCAND];
  __shared__ u32 cnt[32][8];
  // zero 8 KB slice of mask (total NB*NCAND*32 u64 = 262144 = 256 blocks*1024)
  {
    u64* mz = maskz + (size_t)blockIdx.x * 1024;
    for (int x = threadIdx.x; x < 1024; x += 256) mz[x] = 0ull;
    if (threadIdx.x == 0 && blockIdx.x < NB*32) rowflagz[blockIdx.x] = 0ull;
  }
  for (int k = threadIdx.x; k < NCAND; k += 256){
    sm[k]  = csmono[b*NCAND + k];
    stb[k] = ctb[b*NCAND + k];
  }
  __syncthreads();
  int esub = threadIdx.x >> 3;        // 0..31 element within block
  int ssub = threadIdx.x & 7;         // 0..7 scan slice
  int id = blk*32 + esub;
  u32 ms = sm[id];
  u64 mt = stb[id];
  u32 r = 0;
  #pragma unroll 8
  for (int it = 0; it < 256; ++it){
    int m = it*8 + ssub;
    u32 s2 = sm[m]; u64 t2 = stb[m];
    r += ((s2 > ms) || (s2 == ms && t2 < mt)) ? 1u : 0u;
  }
  cnt[esub][ssub] = r;
  __syncthreads();
  if (ssub == 0){
    u32 rank = 0;
    #pragma unroll
    for (int q = 0; q < 8; ++q) rank += cnt[esub][q];
    int gsrc = b*NCAND + id;
    int gdst = b*NCAND + (int)rank;
    sscore[gdst] = cscore[gsrc];
    svalid[gdst] = cvalid[gsrc];
    float b0 = cbox[(size_t)gsrc*5+0], b1 = cbox[(size_t)gsrc*5+1];
    float b2 = cbox[(size_t)gsrc*5+2], b3 = cbox[(size_t)gsrc*5+3];
    float b4 = cbox[(size_t)gsrc*5+4];
    float* sb = sbox + (size_t)gdst*5;
    sb[0]=b0; sb[1]=b1; sb[2]=b2; sb[3]=b3; sb[4]=b4;
    int lvl = (int)((mt >> 50) & 3ull);
    // per-(img,lvl) rank list -- plain store, slot = id&511 (bijective)
    lvlidx[(u32)(b*4 + (id >> 9))*KSEL + (u32)(id & 511)] = (u32)rank;
    float offv = (float)lvl * LVL_OFF_F;
    float cx = b0 + offv, cy = b1 + offv, w=b2, h=b3, ang=b4;
    float cc = cosf(ang), sn = sinf(ang);
    float hx = 0.5f*w, hy = 0.5f*h;
    float x0 = cx + hx*cc - hy*sn, y0 = cy + hx*sn + hy*cc;
    float x1 = cx - hx*cc - hy*sn, y1 = cy - hx*sn + hy*cc;
    float x2 = cx - hx*cc + hy*sn, y2 = cy - hx*sn - hy*cc;
    float x3 = cx + hx*cc + hy*sn, y3 = cy + hx*sn - hy*cc;
    float minx = fminf(fminf(x0,x1),fminf(x2,x3));
    float maxx = fmaxf(fmaxf(x0,x1),fmaxf(x2,x3));
    float miny = fminf(fminf(y0,y1),fminf(y2,y3));
    float maxy = fmaxf(fmaxf(y0,y1),fmaxf(y2,y3));
    float* g = geom + (size_t)gdst*16;
    g[0]=minx; g[1]=maxx; g[2]=miny; g[3]=maxy; g[4]=w*h;
    g[5]=x0; g[6]=y0; g[7]=x1; g[8]=y1; g[9]=x2; g[10]=y2; g[11]=x3; g[12]=y3;
    aabb4[gdst] = make_float4(minx, maxx, miny, maxy);
  }
}

// ---------------------------------------------------------------------------
// K5: level-grouped pair scan. Each block owns 4 mirrored rows of one
// (img,lvl) 512-entry list; AABBs+areas staged in LDS (inner loop has no
// memory latency). Survivor filter is the exact-safe IoU upper bound
// iou>TH  =>  (1+TH)*interAABB > TH*(Ai+Aj); only survivors get the full
// clip. Cross-level pairs are impossible (LVL_OFF construction).
// ---------------------------------------------------------------------------
__device__ __forceinline__ void emit_pt(float* ox, float* oy, int oc, float x, float y){
  #pragma unroll
  for (int s = 0; s < 8; ++s) if (s == oc){ ox[s] = x; oy[s] = y; }
}

__device__ float quad_inter(const float* ca, const float* cb){
  float px[8], py[8];
  #pragma unroll
  for (int q = 0; q < 8; ++q){ px[q]=0.f; py[q]=0.f; }
  #pragma unroll
  for (int q = 0; q < 4; ++q){ px[q]=ca[2*q]; py[q]=ca[2*q+1]; }
  int cnt = 4;
  #pragma unroll
  for (int e = 0; e < 4; ++e){
    float p1x = cb[2*e],         p1y = cb[2*e+1];
    float p2x = cb[(2*e+2)&7],   p2y = cb[(2*e+3)&7];
    float ex = p2x-p1x, ey = p2y-p1y;
    float d[8];
    #pragma unroll
    for (int q = 0; q < 8; ++q) d[q] = ex*(py[q]-p1y) - ey*(px[q]-p1x);
    float ox[8], oy[8];
    #pragma unroll
    for (int q = 0; q < 8; ++q){ ox[q]=0.f; oy[q]=0.f; }
    int oc = 0;
    #pragma unroll
    for (int q = 0; q < 8; ++q){
      if (q < cnt){
        bool last = (q+1 >= cnt);
        float dn  = last ? d[0]  : d[(q+1)&7];
        bool in0 = (d[q] >= 0.0f), in1 = (dn >= 0.0f);
        if (in0){ emit_pt(ox,oy,oc,px[q],py[q]); oc++; }
        if (in0 != in1){
          float pnx = last ? px[0] : px[(q+1)&7];
          float pny = last ? py[0] : py[(q+1)&7];
          float den = d[q] - dn;
          float t = d[q] / ((den == 0.0f) ? 1.0f : den);
          emit_pt(ox,oy,oc, px[q] + t*(pnx-px[q]), py[q] + t*(pny-py[q]));
          oc++;
        }
      }
    }
    cnt = (oc > 8) ? 8 : oc;
    #pragma unroll
    for (int q = 0; q < 8; ++q){ px[q]=ox[q]; py[q]=oy[q]; }
  }
  if (cnt < 3) return 0.0f;
  float s = 0.0f;
  #pragma unroll
  for (int q = 0; q < 8; ++q){
    if (q < cnt){
      bool last = (q+1 >= cnt);
      float pnx = last ? px[0] : px[(q+1)&7];
      float pny = last ? py[0] : py[(q+1)&7];
      s += px[q]*pny - pnx*py[q];
    }
  }
  return 0.5f*fabsf(s);
}

__global__ __launch_bounds__(256) void k5_pairs(
    const u32* __restrict__ lvlidx,
    const float4* __restrict__ aabb4, const float* __restrict__ geom,
    u64* __restrict__ mask, u64* __restrict__ rowflag)
{
  __shared__ u32   s_idx[KSEL];          // 2 KB ranks of this (img,lvl)
  __shared__ float4 s_ab[KSEL];          // 8 KB AABBs
  __shared__ float  s_ar[KSEL];          // 2 KB areas
  __shared__ u32   lbuf[1024];           // 4 KB; max pairs/block = 1022
  __shared__ u32 lcnt;
  const int t = threadIdx.x;
  if (t == 0) lcnt = 0;
  int img = blockIdx.x >> 9;             // 512 blocks per image
  int r9  = blockIdx.x & 511;
  int lvl = r9 >> 7;                     // 128 blocks per level
  int kk  = r9 & 127;
  int lane = t & 63;
  const int base = (img*4 + lvl)*KSEL;
  for (int q = t; q < KSEL; q += 256){
    u32 rk = lvlidx[base + q];
    s_idx[q] = rk;
    s_ab[q]  = aabb4[img*NCAND + rk];
    s_ar[q]  = geom[((size_t)(img*NCAND + rk))*16 + 4];
  }
  __syncthreads();
  int rows[4] = {2*kk, 2*kk + 1, 510 - 2*kk, 511 - 2*kk};
  #pragma unroll
  for (int r = 0; r < 4; ++r){
    int p = rows[r];
    float4 gi = s_ab[p];
    float  ai = s_ar[p];
    for (int q = p + 1 + t; q < KSEL; q += 256){
      float4 gj = s_ab[q];
      float w = fminf(gi.y, gj.y) - fmaxf(gi.x, gj.x);
      float h = fminf(gi.w, gj.w) - fmaxf(gi.z, gj.z);
      bool pass = (w > 0.0f) && (h > 0.0f);
      if (pass){
        float iA = w*h;
        float S  = ai + s_ar[q];
        // exact-safe: iou>TH implies (1+TH)*iA > TH*S; keep with slack
        pass = ((1.0f + NMS_TH)*iA >= NMS_TH*S*(1.0f - 1e-5f));
      }
      u64 bm = __ballot(pass);
      if (bm){
        int leader = __ffsll((long long)bm) - 1;
        u32 bs = 0;
        if (lane == leader) bs = atomicAdd(&lcnt, (u32)__popcll(bm));
        bs = (u32)__shfl((int)bs, leader);
        if (pass){
          u32 off = (u32)__popcll(bm & ((1ull << lane) - 1ull));
          lbuf[bs + off] = (u32)((p << 9) | q);
        }
      }
    }
  }
  __syncthreads();
  u32 n = lcnt;
  for (u32 x = t; x < n; x += 256){
    u32 pr = lbuf[x];
    int p = (int)(pr >> 9), q = (int)(pr & 511);
    u32 ri = s_idx[p], rj = s_idx[q];
    u32 i = ri < rj ? ri : rj;
    u32 j = ri < rj ? rj : ri;
    const float* gi = geom + ((size_t)(img*NCAND + (int)i))*16;
    const float* gj = geom + ((size_t)(img*NCAND + (int)j))*16;
    float inter = quad_inter(gi+5, gj+5);
    float iou = inter / (gi[4] + gj[4] - inter + 1e-7f);
    if (iou > NMS_TH){
      atomicOr(&mask[((size_t)(img*NCAND + (int)i))*32 + (j >> 6)], 1ull << (j & 63));
      atomicOr(&rowflag[(size_t)img*32 + (i >> 6)], 1ull << (i & 63));
    }
  }
}

// ---------------------------------------------------------------------------
// K6: sparse greedy suppression + output (R2-proven version, 8-deep).
// ---------------------------------------------------------------------------
__global__ __launch_bounds__(1024) void k6_nms_out(
    const u64* __restrict__ mask, const u64* __restrict__ rowflag,
    const u8* __restrict__ svalid,
    const float* __restrict__ sbox, const float* __restrict__ sscore,
    float* __restrict__ out)
{
  int b = blockIdx.x;
  __shared__ u32 fid[NCAND];
  __shared__ u32 wcnt[32], wpref[32];
  __shared__ u64 s_kept[32];
  __shared__ u32 pref[32];
  __shared__ u32 s_F;
  int t = threadIdx.x;
  int wid = t >> 6, lane = t & 63;

  // ---- compact flagged row ids (ascending: word-major, bit-major) ----
  if (t < 32) wcnt[t] = (u32)__popcll(rowflag[b*32 + t]);
  __syncthreads();
  if (t == 0){
    u32 run = 0;
    for (int w = 0; w < 32; ++w){ wpref[w] = run; run += wcnt[w]; }
    s_F = run;
  }
  __syncthreads();
  if (t < 32){
    u64 fw = rowflag[b*32 + t];
    u32 o = wpref[t];
    while (fw){
      int bpos = __builtin_ctzll(fw);
      fid[o++] = (u32)(t*64 + bpos);
      fw &= fw - 1;
    }
  }
  // zero-fill output concurrently (independent of the walk)
  for (int x = t; x < POSTN*5; x += 1024) out[(size_t)b*POSTN*5 + x] = 0.0f;
  for (int x = t; x < POSTN;   x += 1024) out[(size_t)NB*POSTN*5 + b*POSTN + x] = 0.0f;
  __syncthreads();

  if (wid == 0){
    // sup init from svalid: lane l<32 builds word l (lanes 32-63 mirror)
    u32 slo = 0, shi = 0;
    {
      int wl = lane & 31;
      u64 w = 0;
      for (int q = 0; q < 64; ++q)
        if (!svalid[b*NCAND + wl*64 + q]) w |= (1ull << q);
      slo = (u32)w; shi = (u32)(w >> 32);
    }
    u32 F = s_F;
    const u64* mb = mask + ((size_t)b*NCAND)*32;
    for (u32 f = 0; f < F; f += 8){
      u32 myfid = 0;
      if (f + (lane & 7) < F) myfid = fid[f + (lane & 7)];
      // prefetch the 8 rows (lane&31 owns one u64 word per row)
      u64 v[8];
      #pragma unroll
      for (int q = 0; q < 8; ++q){
        if (f + q < F){
          u32 fq = (u32)__builtin_amdgcn_readlane((int)myfid, q);
          v[q] = mb[(size_t)fq*32 + (lane & 31)];
        } else v[q] = 0ull;
      }
      #pragma unroll
      for (int q = 0; q < 8; ++q){
        if (f + q < F){
          u32 i = (u32)__builtin_amdgcn_readlane((int)myfid, q);
          int wi = (int)(i >> 6);                  // wave-uniform
          u32 wlo = (u32)__builtin_amdgcn_readlane((int)slo, wi);
          u32 whi = (u32)__builtin_amdgcn_readlane((int)shi, wi);
          u64 w = ((u64)whi << 32) | wlo;
          u32 keep = (u32)((~w >> (i & 63)) & 1ull);
          u64 vm = v[q] & (0ull - (u64)keep);      // branchless
          slo |= (u32)vm; shi |= (u32)(vm >> 32);
        }
      }
    }
    if (lane < 32) s_kept[lane] = ~(((u64)shi << 32) | slo);
  }
  __syncthreads();

  if (t < 32) pref[t] = (u32)__popcll(s_kept[t]);
  __syncthreads();
  if (t == 0){
    u32 run = 0;
    for (int w = 0; w < 32; ++w){ u32 tv = pref[w]; pref[w] = run; run += tv; }
  }
  __syncthreads();
  for (int i = t; i < NCAND; i += 1024){
    u64 kw = s_kept[i >> 6];
    if ((kw >> (i & 63)) & 1ull){
      u32 rank = pref[i >> 6] + (u32)__popcll(kw & ((1ull << (i & 63)) - 1ull));
      if (rank < POSTN){
        const float* bp = sbox + ((size_t)(b*NCAND + i))*5;
        float* op = out + ((size_t)(b*POSTN + rank))*5;
        op[0]=bp[0]; op[1]=bp[1]; op[2]=bp[2]; op[3]=bp[3]; op[4]=bp[4];
        out[(size_t)NB*POSTN*5 + b*POSTN + rank] = sscore[b*NCAND + i];
      }
    }
  }
}

// ---------------------------------------------------------------------------
extern "C" void kernel_launch(void* const* d_in, const int* in_sizes, int n_in,
                              void* d_out, int out_size, void* d_ws, size_t ws_size,
                              hipStream_t stream)
{
  (void)out_size; (void)ws_size;
  const float *obj[4] = {nullptr,nullptr,nullptr,nullptr};
  const float *dlt[4] = {nullptr,nullptr,nullptr,nullptr};
  const float *anchors = nullptr;
  for (int i = 0; i < n_in; ++i){
    int s = in_sizes[i];
    const float* p = (const float*)d_in[i];
    switch (s){
      case 786432:  obj[0] = p; break;
      case 4718592: dlt[0] = p; break;
      case 196608:  obj[1] = p; break;
      case 1179648: dlt[1] = p; break;
      case 49152:   obj[2] = p; break;
      case 294912:  dlt[2] = p; break;
      case 12288:   obj[3] = p; break;
      case 73728:   dlt[3] = p; break;
      case 5222400: anchors = p; break;
      default: break;
    }
  }

  char* wsb = (char*)d_ws;
  size_t off = 0;
  auto alloc = [&](size_t bytes)->void*{
    size_t cur = (off + 255) & ~(size_t)255;
    off = cur + bytes;
    return (void*)(wsb + cur);
  };
  int*   cand_j = (int*)  alloc(16*KSEL*sizeof(int));
  float* cscore = (float*)alloc((size_t)NB*NCAND*sizeof(float));
  u32*   csmono = (u32*)  alloc((size_t)NB*NCAND*sizeof(u32));
  u64*   ctb    = (u64*)  alloc((size_t)NB*NCAND*sizeof(u64));
  float* cbox   = (float*)alloc((size_t)NB*NCAND*5*sizeof(float));
  u8*    cvalid = (u8*)   alloc((size_t)NB*NCAND);
  float* sscore = (float*)alloc((size_t)NB*NCAND*sizeof(float));
  float* sbox   = (float*)alloc((size_t)NB*NCAND*5*sizeof(float));
  u8*    svalid = (u8*)   alloc((size_t)NB*NCAND);
  float* geom   = (float*)alloc((size_t)NB*NCAND*16*sizeof(float));
  float4* aabb4 = (float4*)alloc((size_t)NB*NCAND*sizeof(float4));
  u64*   gtie   = (u64*)  alloc((size_t)16*EQCAP*sizeof(u64));
  u64*   maskp  = (u64*)  alloc((size_t)NB*NCAND*32*sizeof(u64));   // zeroed by k4
  u64*   rowflag= (u64*)  alloc((size_t)NB*32*sizeof(u64));         // zeroed by k4
  u32*   lvlidx = (u32*)  alloc((size_t)16*KSEL*sizeof(u32));       // written by k4
  u32*   gb0    = (u32*)  alloc(16*sizeof(u32));
  u32*   gcA    = (u32*)  alloc(16*sizeof(u32));
  // ---- contiguous zero region (memset): hist16 | done16 | emitc | tiec ----
  u32*   hist16 = (u32*)  alloc((size_t)16*BINS*sizeof(u32));
  u32*   done16 = (u32*)  alloc(16*sizeof(u32));
  u32*   emitc  = (u32*)  alloc(16*sizeof(u32));
  u32*   tiec   = (u32*)  alloc(16*sizeof(u32));
  size_t zero_len = (size_t)((wsb + off) - (char*)hist16);

  hipMemsetAsync(hist16, 0, zero_len, stream);

  hipLaunchKernelGGL(k1_hist_thresh, dim3(K1_BLOCKS), dim3(1024), 0, stream,
                     obj[0], obj[1], obj[2], obj[3], hist16, done16, gb0, gcA);
  hipLaunchKernelGGL(k2_classify, dim3(K1_BLOCKS), dim3(1024), 0, stream,
                     obj[0], obj[1], obj[2], obj[3], gb0, emitc, tiec,
                     cand_j, gtie);
  hipLaunchKernelGGL(k3_tie_decode, dim3(16), dim3(512), 0, stream,
                     gtie, tiec, gcA, cand_j,
                     obj[0], obj[1], obj[2], obj[3],
                     dlt[0], dlt[1], dlt[2], dlt[3],
                     anchors, cscore, csmono, ctb, cbox, cvalid);
  hipLaunchKernelGGL(k4_rank, dim3(256), dim3(256), 0, stream,
                     csmono, ctb, cscore, cbox, cvalid, sscore, sbox, geom,
                     aabb4, svalid, maskp, rowflag, lvlidx);
  hipLaunchKernelGGL(k5_pairs, dim3(K5_BLOCKS), dim3(256), 0, stream,
                     lvlidx, aabb4, geom, maskp, rowflag);
  hipLaunchKernelGGL(k6_nms_out, dim3(4), dim3(1024), 0, stream,
                     maskp, rowflag, svalid, sbox, sscore, (float*)d_out);
}